// Round 2
// baseline (684.708 us; speedup 1.0000x reference)
//
#include <hip/hip_runtime.h>

// Problem: x [16, 512, 512, 32] f32 -> out [16, 512, 512, 1] f32
// out[b,h,w] = max over shifts S = {(0,0),(0,1),(1,0),(1,1),(0,2),(2,0),(2,2)}
//              of M[b, h-di, w-dj],  M = channel-max of x, OOB -> 0 (zero pad).
// Memory-bound: 537 MB read + 16.8 MB write -> ~88 us floor at 6.3 TB/s.
//
// R2 change: wave-cooperative phase-1 loads. 8 lanes per pixel, one float4
// per lane -> each wave instruction reads a contiguous 1 KiB (8 cache lines)
// instead of 64 partial lines (R1 pattern thrashed L1: 8x L2 re-reads).
// Channel max = 3 in-lane v_max + 3 shfl_xor (ds_swizzle) across the 8-lane
// group.

#define HH 512
#define WW 512
#define CC 32
#define TILE 64
#define REG (TILE + 2)       // 66: backward halo of 2 in h and w
#define NPIX (REG * REG)     // 4356 region pixels
#define NLOAD (NPIX * 8)     // 34848 float4 loads (8 per pixel)

__global__ __launch_bounds__(256) void maxassign2d_kernel(
    const float* __restrict__ x, float* __restrict__ out) {
  __shared__ float m[NPIX];  // channel-max of the 66x66 region, stride 66

  const int b  = blockIdx.z;
  const int h0 = blockIdx.y * TILE;
  const int w0 = blockIdx.x * TILE;
  const int tid = threadIdx.x;

  const float* __restrict__ img = x + (size_t)b * HH * WW * CC;

  // ---- Phase 1: channel-max into LDS, fully coalesced ----
  // q = tid + k*256; lane group = q&7 (aligned: 256 % 8 == 0), pixel = q>>3.
  // Lanes 8j..8j+7 read the 8 float4s of pixel (pix+j) -> contiguous 1 KiB
  // per wave instruction (modulo region-row breaks every 66 pixels).
#pragma unroll 4
  for (int q = tid; q < NLOAD; q += 256) {
    const int pix = q >> 3;
    const int f4  = q & 7;
    const int rr  = pix / REG;        // magic-mul, no HW divide
    const int cc  = pix - rr * REG;
    const int h = h0 + rr - 2;        // only low side can go OOB (448+65-2=511)
    const int w = w0 + cc - 2;
    float s = 0.0f;                   // zero pad joins the max at borders
    if (h >= 0 && w >= 0) {
      const float4 a =
          *(const float4*)(img + ((size_t)h * WW + w) * CC + f4 * 4);
      s = fmaxf(fmaxf(a.x, a.y), fmaxf(a.z, a.w));
    }
    // OOB status is uniform within an 8-lane group (same pixel), so the
    // shuffles run convergently with s=0 on padded pixels.
    s = fmaxf(s, __shfl_xor(s, 1, 64));
    s = fmaxf(s, __shfl_xor(s, 2, 64));
    s = fmaxf(s, __shfl_xor(s, 4, 64));
    if (f4 == 0) m[pix] = s;          // 8 writers/wave, consecutive addrs
  }
  __syncthreads();

  // ---- Phase 2: 7-way backward-shift max over the LDS tile ----
  // Output (r,c) sits at region coord (r+2, c+2); shift (di,dj) reads
  // region (r+2-di, c+2-dj). Stores: 64 consecutive floats per wave.
  for (int p = tid; p < TILE * TILE; p += 256) {
    const int r = p >> 6;
    const int c = p & (TILE - 1);
    const float* base = &m[r * REG + c];
    float v = base[2 * REG + 2];              // (0,0)
    v = fmaxf(v, base[2 * REG + 1]);          // (0,1)
    v = fmaxf(v, base[1 * REG + 2]);          // (1,0)
    v = fmaxf(v, base[1 * REG + 1]);          // (1,1)
    v = fmaxf(v, base[2 * REG + 0]);          // (0,2)
    v = fmaxf(v, base[0 * REG + 2]);          // (2,0)
    v = fmaxf(v, base[0 * REG + 0]);          // (2,2)
    out[((size_t)b * HH + (h0 + r)) * WW + (w0 + c)] = v;
  }
}

extern "C" void kernel_launch(void* const* d_in, const int* in_sizes, int n_in,
                              void* d_out, int out_size, void* d_ws, size_t ws_size,
                              hipStream_t stream) {
  const float* x = (const float*)d_in[0];
  float* out = (float*)d_out;
  const int B = in_sizes[0] / (HH * WW * CC);  // = 16
  dim3 grid(WW / TILE, HH / TILE, B);          // (8, 8, 16) = 1024 blocks
  maxassign2d_kernel<<<grid, 256, 0, stream>>>(x, out);
}